// Round 1
// baseline (212.512 us; speedup 1.0000x reference)
//
#include <hip/hip_runtime.h>

#define BB   128   // batch
#define LBL  1024  // label size
#define TT   255   // max_num_trials
#define CH   8     // chunk-blocks per row
#define NTHREADS 256

__global__ __launch_bounds__(NTHREADS) void warp_loss_kernel(
    const float* __restrict__ input,   // [B][LBL]
    const float* __restrict__ u,       // [B][LBL][T]
    const int*   __restrict__ target,  // [B][LBL]
    float* __restrict__ out)           // [1], pre-zeroed
{
    __shared__ float         s_input[LBL];
    __shared__ float         s_negscore[LBL];
    __shared__ unsigned char s_target[LBL];
    __shared__ float         s_rw[256];
    __shared__ float         s_wavesum[NTHREADS / 64];
    __shared__ int           s_nneg;
    __shared__ float         s_margin;

    const int b    = blockIdx.x;
    const int ch   = blockIdx.y;
    const int tid  = threadIdx.x;
    const int lane = tid & 63;
    const int wv   = tid >> 6;   // wave in block: 0..3

    // ---- issue row loads into registers first (overlap HBM latency with rw compute)
    const float* inrow = input  + (size_t)b * LBL;
    const int*   tgrow = target + (size_t)b * LBL;
    float rin[LBL / NTHREADS];
    int   rtg[LBL / NTHREADS];
#pragma unroll
    for (int i = 0; i < LBL / NTHREADS; ++i) {
        int j = tid + i * NTHREADS;
        rin[i] = inrow[j];
        rtg[i] = tgrow[j];
    }

    // ---- rank_weights[i] = 1 + i + H_i (double accumulation; threshold is ~2% so
    //      any cumsum-order difference vs jnp f32 cumsum is negligible)
    {
        double h = 0.0;
        for (int k = 1; k <= tid; ++k) h += 1.0 / (double)k;
        s_rw[tid] = (float)(1.0 + (double)tid + h);
    }

#pragma unroll
    for (int i = 0; i < LBL / NTHREADS; ++i) {
        int j = tid + i * NTHREADS;
        s_input[j]  = rin[i];
        s_target[j] = (unsigned char)(rtg[i] != 0);
    }
    __syncthreads();

    // ---- wave 0: stable compaction of negative-label scores (matches argsort order)
    if (wv == 0) {
        int base = 0;
        for (int it = 0; it < LBL / 64; ++it) {
            int j = it * 64 + lane;
            bool isneg = (s_target[j] == 0);
            unsigned long long m = __ballot(isneg);
            int pfx = __popcll(m & ((1ull << lane) - 1ull));
            if (isneg) s_negscore[base + pfx] = s_input[j];
            base += __popcll(m);
        }
        if (lane == 0) {
            s_nneg = base;
            if (base == 0) s_negscore[0] = s_input[0];  // argsort(all-ones) = identity
        }
    }
    // ---- wave 1: margin_term = sum_j (1 - pos*x + neg*x)
    if (wv == 1) {
        float acc = 0.f;
        for (int j = lane; j < LBL; j += 64) {
            float x = s_input[j];
            acc += 1.0f + (s_target[j] ? -x : x);
        }
#pragma unroll
        for (int off = 32; off > 0; off >>= 1) acc += __shfl_down(acc, off, 64);
        if (lane == 0) s_margin = acc;
    }
    __syncthreads();

    const int   nneg  = s_nneg;
    const float nnegf = (float)nneg;
    const int   kmax  = nneg > 0 ? nneg - 1 : 0;

    // ---- phase B: one wave per positive label, 64 trials per coalesced batch
    float Lsum = 0.f;                              // wave-uniform
    const int WPR  = CH * (NTHREADS / 64);         // waves per row
    const int wrow = ch * (NTHREADS / 64) + wv;    // this wave's index in the row
    for (int j = wrow; j < LBL; j += WPR) {
        if (!s_target[j]) continue;
        const float score = s_input[j];
        const float* urow = u + ((size_t)b * LBL + j) * TT;
        int num_trials = TT;
#pragma unroll 1
        for (int t0 = 0; t0 < TT; t0 += 64) {
            int t = t0 + lane;
            bool ok = false;
            if (t < TT) {
                float uv = urow[t];
                int k = (int)(uv * nnegf);          // exact f32 mul + trunc, matches ref
                k = k < kmax ? k : kmax;
                ok = (s_negscore[k] >= score);      // margin >= 0
            }
            unsigned long long m = __ballot(ok);
            if (m) { num_trials = t0 + __ffsll(m); break; }  // first success + 1
        }
        int r = TT / num_trials;                    // 1..255
        Lsum += s_rw[r];
    }

    if (lane == 0) s_wavesum[wv] = Lsum;
    __syncthreads();
    if (tid == 0) {
        float tot = 0.f;
#pragma unroll
        for (int w = 0; w < NTHREADS / 64; ++w) tot += s_wavesum[w];
        atomicAdd(out, tot * s_margin);
    }
}

extern "C" void kernel_launch(void* const* d_in, const int* in_sizes, int n_in,
                              void* d_out, int out_size, void* d_ws, size_t ws_size,
                              hipStream_t stream) {
    const float* input  = (const float*)d_in[0];
    const float* u      = (const float*)d_in[1];
    const int*   target = (const int*)d_in[2];
    float* out = (float*)d_out;

    hipMemsetAsync(out, 0, sizeof(float) * out_size, stream);

    dim3 grid(BB, CH);
    warp_loss_kernel<<<grid, NTHREADS, 0, stream>>>(input, u, target, out);
}

// Round 3
// 186.568 us; speedup vs baseline: 1.1391x; 1.1391x over previous
//
#include <hip/hip_runtime.h>

#define BB   128   // batch
#define LBL  1024  // label size
#define TT   255   // max_num_trials
#define CH   8     // chunk-blocks per row
#define NTHREADS 256
#define NWAVES (NTHREADS / 64)
#define WPR  (CH * NWAVES)     // waves per row = 32
#define LPW  (LBL / WPR)       // labels per wave = 32

__global__ __launch_bounds__(NTHREADS) void warp_loss_kernel(
    const float* __restrict__ input,   // [B][LBL]
    const float* __restrict__ u,       // [B][LBL][T]
    const int*   __restrict__ target,  // [B][LBL]
    float* __restrict__ out)           // [1], zeroed by memset
{
    __shared__ float         s_input[LBL];
    __shared__ float         s_negscore[LBL];
    __shared__ unsigned char s_target[LBL];
    __shared__ float         s_rw[NTHREADS];
    __shared__ float         s_wavesum[NWAVES];
    __shared__ int           s_nneg;
    __shared__ float         s_margin;

    const int b    = blockIdx.x;
    const int ch   = blockIdx.y;
    const int tid  = threadIdx.x;
    const int lane = tid & 63;
    const int wv   = tid >> 6;

    // ---- issue row loads; their latency hides under the rank-weight scan below
    const float* inrow = input  + (size_t)b * LBL;
    const int*   tgrow = target + (size_t)b * LBL;
    float rin[LBL / NTHREADS];
    int   rtg[LBL / NTHREADS];
#pragma unroll
    for (int i = 0; i < LBL / NTHREADS; ++i) {
        int j = tid + i * NTHREADS;
        rin[i] = inrow[j];
        rtg[i] = tgrow[j];
    }

    // ---- rank_weights = f32 cumsum(incr) via Hillis-Steele scan (matches ref's
    //      jnp f32 cumsum; replaces 255 serial f64 divisions per thread)
    s_rw[tid] = (tid == 0) ? 1.0f : 1.0f + 1.0f / (float)tid;
    __syncthreads();
#pragma unroll
    for (int off = 1; off < NTHREADS; off <<= 1) {
        float add = (tid >= off) ? s_rw[tid - off] : 0.0f;
        __syncthreads();
        s_rw[tid] += add;
        __syncthreads();
    }

#pragma unroll
    for (int i = 0; i < LBL / NTHREADS; ++i) {
        int j = tid + i * NTHREADS;
        s_input[j]  = rin[i];
        s_target[j] = (unsigned char)(rtg[i] != 0);
    }
    __syncthreads();

    // ---- per-wave positive-label mask; issue ALL first-batch u loads now so the
    //      HBM latency hides under wave0's compaction + the barrier
    const int wrow = ch * NWAVES + wv;
    unsigned long long pm;
    {
        bool p = (lane < LPW) && (s_target[wrow + lane * WPR] != 0);
        pm = __ballot(p);
    }
    const float* ubase = u + (size_t)b * LBL * TT;
    float uv[LPW];                      // statically indexed (full unroll) -> registers
#pragma unroll
    for (int i = 0; i < LPW; ++i) {
        if ((pm >> i) & 1) {
            int j = wrow + i * WPR;
            uv[i] = ubase[(size_t)j * TT + lane];
        }
    }

    // ---- wave 0: stable compaction of negative-label scores (matches argsort order)
    if (wv == 0) {
        int base = 0;
        for (int it = 0; it < LBL / 64; ++it) {
            int j = it * 64 + lane;
            bool isneg = (s_target[j] == 0);
            unsigned long long m = __ballot(isneg);
            int pfx = __popcll(m & ((1ull << lane) - 1ull));
            if (isneg) s_negscore[base + pfx] = s_input[j];
            base += __popcll(m);
        }
        if (lane == 0) {
            s_nneg = base;
            if (base == 0) s_negscore[0] = s_input[0];
        }
    }
    // ---- wave 1: margin_term = sum_j (1 - pos*x + neg*x)
    if (wv == 1) {
        float acc = 0.f;
        for (int j = lane; j < LBL; j += 64) {
            float x = s_input[j];
            acc += 1.0f + (s_target[j] ? -x : x);
        }
#pragma unroll
        for (int off = 32; off > 0; off >>= 1) acc += __shfl_down(acc, off, 64);
        if (lane == 0) s_margin = acc;
    }
    __syncthreads();

    const int   nneg  = s_nneg;
    const float nnegf = (float)nneg;
    const int   kmax  = nneg > 0 ? nneg - 1 : 0;

    // ---- consume prefetched batches oldest-first (compiler emits counted vmcnt waits)
    float Lsum = 0.f;
#pragma unroll
    for (int i = 0; i < LPW; ++i) {
        if (!((pm >> i) & 1)) continue;
        const int   j     = wrow + i * WPR;
        const float score = s_input[j];
        int k = (int)(uv[i] * nnegf);           // exact f32 mul + trunc, matches ref
        k = k < kmax ? k : kmax;
        bool ok = (s_negscore[k] >= score);     // margin >= 0
        unsigned long long m = __ballot(ok);
        int num_trials;
        if (m) {
            num_trials = __ffsll(m);            // first success + 1 (t0 == 0)
        } else {
            num_trials = TT;                    // rare slow path: trials 64..254
#pragma unroll 1
            for (int t0 = 64; t0 < TT; t0 += 64) {
                int t = t0 + lane;
                bool ok2 = false;
                if (t < TT) {
                    float uvv = ubase[(size_t)j * TT + t];
                    int kk = (int)(uvv * nnegf);
                    kk = kk < kmax ? kk : kmax;
                    ok2 = (s_negscore[kk] >= score);
                }
                unsigned long long m2 = __ballot(ok2);
                if (m2) { num_trials = t0 + __ffsll(m2); break; }
            }
        }
        Lsum += s_rw[TT / num_trials];
    }

    if (lane == 0) s_wavesum[wv] = Lsum;
    __syncthreads();
    if (tid == 0) {
        float tot = 0.f;
#pragma unroll
        for (int w = 0; w < NWAVES; ++w) tot += s_wavesum[w];
        atomicAdd(out, tot * s_margin);
    }
}

extern "C" void kernel_launch(void* const* d_in, const int* in_sizes, int n_in,
                              void* d_out, int out_size, void* d_ws, size_t ws_size,
                              hipStream_t stream) {
    const float* input  = (const float*)d_in[0];
    const float* u      = (const float*)d_in[1];
    const int*   target = (const int*)d_in[2];
    float* out = (float*)d_out;

    hipMemsetAsync(out, 0, sizeof(float) * out_size, stream);

    dim3 grid(BB, CH);
    warp_loss_kernel<<<grid, NTHREADS, 0, stream>>>(input, u, target, out);
}

// Round 5
// 181.241 us; speedup vs baseline: 1.1725x; 1.0294x over previous
//
#include <hip/hip_runtime.h>

#define BB   128   // batch
#define LBL  1024  // label size
#define TT   255   // max_num_trials
#define CH   8     // chunk-blocks per row
#define NTHREADS 256
#define NWAVES (NTHREADS / 64)
#define WPR  (CH * NWAVES)     // waves per row = 32
#define LPW  (LBL / WPR)       // labels per wave = 32

__global__ __launch_bounds__(NTHREADS) void warp_loss_main(
    const float* __restrict__ input,   // [B][LBL]
    const float* __restrict__ u,       // [B][LBL][T]
    const int*   __restrict__ target,  // [B][LBL]
    float* __restrict__ partial)       // [BB*CH] in d_ws (no pre-zero needed)
{
    __shared__ float         s_input[LBL];
    __shared__ float         s_negscore[LBL];
    __shared__ unsigned char s_target[LBL];
    __shared__ float         s_rw[NTHREADS];
    __shared__ float         s_wtot[NWAVES];
    __shared__ float         s_wavesum[NWAVES];
    __shared__ int           s_nneg;
    __shared__ float         s_margin;

    const int b    = blockIdx.x;
    const int ch   = blockIdx.y;
    const int tid  = threadIdx.x;
    const int lane = tid & 63;
    const int wv   = tid >> 6;

    // ---- row loads -> LDS immediately (shortest path to enabling the u prefetch)
    const float* inrow = input  + (size_t)b * LBL;
    const int*   tgrow = target + (size_t)b * LBL;
    float rin[LBL / NTHREADS];
    int   rtg[LBL / NTHREADS];
#pragma unroll
    for (int i = 0; i < LBL / NTHREADS; ++i) {
        int j = tid + i * NTHREADS;
        rin[i] = inrow[j];
        rtg[i] = tgrow[j];
    }
#pragma unroll
    for (int i = 0; i < LBL / NTHREADS; ++i) {
        int j = tid + i * NTHREADS;
        s_input[j]  = rin[i];
        s_target[j] = (unsigned char)(rtg[i] != 0);
    }
    __syncthreads();

    // ---- issue ALL first-batch u loads NOW; latency hides under scan+compaction+margin
    const int wrow = ch * NWAVES + wv;
    unsigned long long pm;
    {
        bool p = (lane < LPW) && (s_target[wrow + lane * WPR] != 0);
        pm = __ballot(p);
    }
    const float* ubase = u + (size_t)b * LBL * TT;
    float uv[LPW];                      // statically indexed (full unroll) -> registers
#pragma unroll
    for (int i = 0; i < LPW; ++i) {
        if ((pm >> i) & 1) {
            int j = wrow + i * WPR;
            uv[i] = ubase[(size_t)j * TT + lane];
        }
    }

    // ---- rank_weights cumsum via wave shfl scan (register-only; 2 barriers total
    //      vs 16 for the Hillis-Steele version)
    float acc = (tid == 0) ? 1.0f : 1.0f + 1.0f / (float)tid;
#pragma unroll
    for (int off = 1; off < 64; off <<= 1) {
        float v = __shfl_up(acc, off, 64);
        if (lane >= off) acc += v;
    }
    if (lane == 63) s_wtot[wv] = acc;

    // ---- wave 0: stable compaction of negative-label scores (matches argsort order)
    if (wv == 0) {
        int base = 0;
        for (int it = 0; it < LBL / 64; ++it) {
            int j = it * 64 + lane;
            bool isneg = (s_target[j] == 0);
            unsigned long long m = __ballot(isneg);
            int pfx = __popcll(m & ((1ull << lane) - 1ull));
            if (isneg) s_negscore[base + pfx] = s_input[j];
            base += __popcll(m);
        }
        if (lane == 0) {
            s_nneg = base;
            if (base == 0) s_negscore[0] = s_input[0];  // argsort(all-ones) = identity
        }
    }
    // ---- wave 1: margin_term = sum_j (1 - pos*x + neg*x)
    if (wv == 1) {
        float macc = 0.f;
        for (int j = lane; j < LBL; j += 64) {
            float x = s_input[j];
            macc += 1.0f + (s_target[j] ? -x : x);
        }
#pragma unroll
        for (int off = 32; off > 0; off >>= 1) macc += __shfl_down(macc, off, 64);
        if (lane == 0) s_margin = macc;
    }
    __syncthreads();

    // finalize rank weights: add preceding-wave totals
    {
        float pre = 0.f;
#pragma unroll
        for (int w = 0; w < NWAVES; ++w)
            if (w < wv) pre += s_wtot[w];
        s_rw[tid] = acc + pre;
    }
    __syncthreads();

    const int   nneg  = s_nneg;
    const float nnegf = (float)nneg;
    const int   kmax  = nneg > 0 ? nneg - 1 : 0;

    // ---- consume prefetched batches oldest-first (counted vmcnt waits)
    float Lsum = 0.f;
#pragma unroll
    for (int i = 0; i < LPW; ++i) {
        if (!((pm >> i) & 1)) continue;
        const int   j     = wrow + i * WPR;
        const float score = s_input[j];
        int k = (int)(uv[i] * nnegf);           // exact f32 mul + trunc, matches ref
        k = k < kmax ? k : kmax;
        bool ok = (s_negscore[k] >= score);     // margin >= 0
        unsigned long long m = __ballot(ok);
        int num_trials;
        if (m) {
            num_trials = __ffsll(m);            // first success + 1 (t0 == 0)
        } else {
            num_trials = TT;                    // ~1.5% slow path: trials 64..254
#pragma unroll 1
            for (int t0 = 64; t0 < TT; t0 += 64) {
                int t = t0 + lane;
                bool ok2 = false;
                if (t < TT) {
                    float uvv = ubase[(size_t)j * TT + t];
                    int kk = (int)(uvv * nnegf);
                    kk = kk < kmax ? kk : kmax;
                    ok2 = (s_negscore[kk] >= score);
                }
                unsigned long long m2 = __ballot(ok2);
                if (m2) { num_trials = t0 + __ffsll(m2); break; }
            }
        }
        Lsum += s_rw[TT / num_trials];
    }

    if (lane == 0) s_wavesum[wv] = Lsum;
    __syncthreads();
    if (tid == 0) {
        float tot = 0.f;
#pragma unroll
        for (int w = 0; w < NWAVES; ++w) tot += s_wavesum[w];
        partial[b * CH + ch] = tot * s_margin;  // unconditional write -> poison-safe
    }
}

__global__ __launch_bounds__(256) void warp_loss_reduce(
    const float* __restrict__ partial,  // [BB*CH] = 1024
    float* __restrict__ out)            // [1]
{
    const int tid = threadIdx.x;
    float a = partial[tid] + partial[tid + 256] + partial[tid + 512] + partial[tid + 768];
#pragma unroll
    for (int off = 32; off > 0; off >>= 1) a += __shfl_down(a, off, 64);
    __shared__ float s[4];
    if ((tid & 63) == 0) s[tid >> 6] = a;
    __syncthreads();
    if (tid == 0) out[0] = s[0] + s[1] + s[2] + s[3];
}

extern "C" void kernel_launch(void* const* d_in, const int* in_sizes, int n_in,
                              void* d_out, int out_size, void* d_ws, size_t ws_size,
                              hipStream_t stream) {
    const float* input  = (const float*)d_in[0];
    const float* u      = (const float*)d_in[1];
    const int*   target = (const int*)d_in[2];
    float* out     = (float*)d_out;
    float* partial = (float*)d_ws;      // 4 KB of the workspace

    dim3 grid(BB, CH);
    warp_loss_main<<<grid, NTHREADS, 0, stream>>>(input, u, target, partial);
    warp_loss_reduce<<<1, 256, 0, stream>>>(partial, out);
}